// Round 1
// 450.437 us; speedup vs baseline: 1.2065x; 1.2065x over previous
//
#include <hip/hip_runtime.h>

// Scatter-mean voxel pooling, bucketed single-atomic-pass version.
// N=1e6 points, C=64 channels, K=64 grid (262144 cells, Poisson lambda=3.81).
//
// Round-4 change: replace 6-kernel counting sort (histogram atomics + 3 scans
// + placement atomics + gather-by-order) with direct bucketing:
//   assign:  slot = atomicAdd(&counts[cell],1); bucket[cell*CAP+slot] = pidx
//   reduce:  4 cells/wave, bucket row (2x int4) loaded in parallel with count
//            (2-level dep chain, not 3), 8 clamped feat loads in flight.
// Overflow past CAP=16 (prob ~2.7e-6/cell) goes to a spill list scanned only
// by the rare waves whose count exceeds CAP -> exact results preserved.

#define KGRID  64
#define NCH    64
#define NCELLS (KGRID * KGRID * KGRID)   // 262144
#define CAP    16                        // bucket slots per cell (64 B row)
#define SPILLCAP 8192

__device__ __forceinline__ int cell_of(float px, float py, float pz) {
    int ix = min(max((int)floorf((px + 1.0f) * 32.0f), 0), KGRID - 1);
    int iy = min(max((int)floorf((py + 1.0f) * 32.0f), 0), KGRID - 1);
    int iz = min(max((int)floorf((pz + 1.0f) * 32.0f), 0), KGRID - 1);
    return (ix << 12) | (iy << 6) | iz;
}

__device__ __forceinline__ void fadd4(float4& a, const float4& b) {
    a.x += b.x; a.y += b.y; a.z += b.z; a.w += b.w;
}

// 4 points per thread: 3 float4 loads = 12 floats = 4 points.
__global__ __launch_bounds__(256) void assign_pts(
    const float* __restrict__ pts,
    int* __restrict__ counts,
    int* __restrict__ nspill,
    int* __restrict__ spill,
    int* __restrict__ bucket,
    int n)
{
    int t = blockIdx.x * blockDim.x + threadIdx.x;
    int p0 = t * 4;
    if (p0 >= n) return;
    if (p0 + 4 <= n) {
        const float4* p4 = (const float4*)(pts + (size_t)p0 * 3);
        float4 a = p4[0], b = p4[1], c = p4[2];
        int cid[4];
        cid[0] = cell_of(a.x, a.y, a.z);
        cid[1] = cell_of(a.w, b.x, b.y);
        cid[2] = cell_of(b.z, b.w, c.x);
        cid[3] = cell_of(c.y, c.z, c.w);
        #pragma unroll
        for (int i = 0; i < 4; ++i) {
            int slot = atomicAdd(&counts[cid[i]], 1);
            if (slot < CAP) {
                bucket[(size_t)cid[i] * CAP + slot] = p0 + i;
            } else {
                int s = atomicAdd(nspill, 1);
                if (s < SPILLCAP) { spill[2 * s] = cid[i]; spill[2 * s + 1] = p0 + i; }
            }
        }
    } else {
        for (int p = p0; p < n; ++p) {
            int c = cell_of(pts[3 * p], pts[3 * p + 1], pts[3 * p + 2]);
            int slot = atomicAdd(&counts[c], 1);
            if (slot < CAP) {
                bucket[(size_t)c * CAP + slot] = p;
            } else {
                int s = atomicAdd(nspill, 1);
                if (s < SPILLCAP) { spill[2 * s] = c; spill[2 * s + 1] = p; }
            }
        }
    }
}

// One wave = 4 cells. grp = lane>>4 owns cell wave*4+grp; ch4 = lane&15 spans
// the 64-ch row as float4s. Bucket row address depends only on cell, so the
// two int4 bucket loads issue in parallel with the count load. First 8 point
// rows are fetched with clamped indices (invalid -> entry 0, an L1-hit dup),
// giving 8 independent gather loads in flight per wave. Output write is a
// contiguous 1 KB per wave (4 consecutive cells x 256 B).
__global__ __launch_bounds__(256) void reduce_bucket(
    const float4* __restrict__ feat4,
    const int* __restrict__ counts,
    const int* __restrict__ nspill,
    const int* __restrict__ spill,
    const int* __restrict__ bucket,
    float4* __restrict__ out4)
{
    int lane = threadIdx.x & 63;
    int wave = (int)((blockIdx.x * blockDim.x + threadIdx.x) >> 6);
    int grp  = lane >> 4;
    int ch4  = lane & 15;
    int cell = wave * 4 + grp;          // grid sized exactly: cell < NCELLS

    int cnt = counts[cell];
    const int4* bk = (const int4*)(bucket + (size_t)cell * CAP);
    int4 q0 = bk[0];                    // issues in parallel with counts load
    int4 q1 = bk[1];

    float4 acc = make_float4(0.f, 0.f, 0.f, 0.f);
    if (cnt > 0) {
        int len = min(cnt, CAP);
        int e0 = q0.x;
        int e1 = (len > 1) ? q0.y : e0;
        int e2 = (len > 2) ? q0.z : e0;
        int e3 = (len > 3) ? q0.w : e0;
        int e4 = (len > 4) ? q1.x : e0;
        int e5 = (len > 5) ? q1.y : e0;
        int e6 = (len > 6) ? q1.z : e0;
        int e7 = (len > 7) ? q1.w : e0;
        const float4* fb = feat4 + ch4;
        float4 f0 = fb[(size_t)e0 * 16];
        float4 f1 = fb[(size_t)e1 * 16];
        float4 f2 = fb[(size_t)e2 * 16];
        float4 f3 = fb[(size_t)e3 * 16];
        float4 f4 = fb[(size_t)e4 * 16];
        float4 f5 = fb[(size_t)e5 * 16];
        float4 f6 = fb[(size_t)e6 * 16];
        float4 f7 = fb[(size_t)e7 * 16];
        acc = f0;
        if (len > 1) fadd4(acc, f1);
        if (len > 2) fadd4(acc, f2);
        if (len > 3) fadd4(acc, f3);
        if (len > 4) fadd4(acc, f4);
        if (len > 5) fadd4(acc, f5);
        if (len > 6) fadd4(acc, f6);
        if (len > 7) fadd4(acc, f7);
        if (len > 8) {
            for (int i = 8; i < len; ++i) {
                int p = bucket[(size_t)cell * CAP + i];
                fadd4(acc, fb[(size_t)p * 16]);
            }
        }
        if (cnt > CAP) {                // ~1 cell per grid; exactness guard
            int ns = min(*nspill, SPILLCAP);
            for (int s = 0; s < ns; ++s) {
                if (spill[2 * s] == cell) fadd4(acc, fb[(size_t)spill[2 * s + 1] * 16]);
            }
        }
        float inv = 1.0f / (float)cnt;
        acc.x *= inv; acc.y *= inv; acc.z *= inv; acc.w *= inv;
    }
    out4[(size_t)wave * 64 + lane] = acc;   // == out4[cell*16 + ch4], contiguous
}

extern "C" void kernel_launch(void* const* d_in, const int* in_sizes, int n_in,
                              void* d_out, int out_size, void* d_ws, size_t ws_size,
                              hipStream_t stream)
{
    const float* feat = (const float*)d_in[0];   // (N, 64) fp32
    const float* pts  = (const float*)d_in[1];   // (N, 3)  fp32
    float* out = (float*)d_out;                  // (64,64,64,64) fp32

    const int n = in_sizes[0] / NCH;

    // Workspace (ints): counts | nspill(pad 4) | spill(2*SPILLCAP) | bucket
    // Total: 262144 + 4 + 16384 + 4194304 ints = ~17.3 MB
    int* counts = (int*)d_ws;                    // NCELLS
    int* nspill = counts + NCELLS;               // 1 (+3 pad)
    int* spill  = nspill + 4;                    // 2*SPILLCAP
    int* bucket = spill + 2 * SPILLCAP;          // NCELLS*CAP (16-B aligned)

    hipMemsetAsync(counts, 0, (size_t)(NCELLS + 4) * sizeof(int), stream);

    int t4 = (n + 3) / 4;
    int pblocks = (t4 + 255) / 256;
    assign_pts<<<pblocks, 256, 0, stream>>>(pts, counts, nspill, spill, bucket, n);

    // 65536 waves (4 cells each) = 16384 blocks of 4 waves.
    reduce_bucket<<<NCELLS / 16, 256, 0, stream>>>(
        (const float4*)feat, counts, nspill, spill, bucket, (float4*)out);
}

// Round 2
// 419.456 us; speedup vs baseline: 1.2956x; 1.0739x over previous
//
#include <hip/hip_runtime.h>

// Scatter-mean voxel pooling, bucketed one-atomic-pass, fused cell records.
// N=1e6 points, C=64 channels, K=64 grid (262144 cells, Poisson lambda=3.81).
//
// Round-5 change: counts[] and bucket[] fused into one 64-B record per cell:
//   rec[cell] = { count, slot[0..14] }   (16 ints = exactly one cache line)
// assign's atomicAdd and its dependent slot store now touch the SAME random
// line (1e6 random line touches instead of 2e6); reduce reads count+all slots
// with a single 64-B record load (4x int4 issued together) -> one less
// dependent load stage and no separate counts array. CAP=15: P(overflow) ~
// 1.6e-6/cell; exact via spill list.

#define KGRID  64
#define NCH    64
#define NCELLS (KGRID * KGRID * KGRID)   // 262144
#define CAP    15                        // slots per 64-B record
#define SPILLCAP 8192

__device__ __forceinline__ int cell_of(float px, float py, float pz) {
    int ix = min(max((int)floorf((px + 1.0f) * 32.0f), 0), KGRID - 1);
    int iy = min(max((int)floorf((py + 1.0f) * 32.0f), 0), KGRID - 1);
    int iz = min(max((int)floorf((pz + 1.0f) * 32.0f), 0), KGRID - 1);
    return (ix << 12) | (iy << 6) | iz;
}

__device__ __forceinline__ void fadd4(float4& a, const float4& b) {
    a.x += b.x; a.y += b.y; a.z += b.z; a.w += b.w;
}

// 4 points per thread: 3 float4 loads = 12 floats = 4 points.
__global__ __launch_bounds__(256) void assign_pts(
    const float* __restrict__ pts,
    int* __restrict__ rec,
    int* __restrict__ nspill,
    int* __restrict__ spill,
    int n)
{
    int t = blockIdx.x * blockDim.x + threadIdx.x;
    int p0 = t * 4;
    if (p0 >= n) return;
    if (p0 + 4 <= n) {
        const float4* p4 = (const float4*)(pts + (size_t)p0 * 3);
        float4 a = p4[0], b = p4[1], c = p4[2];
        int cid[4];
        cid[0] = cell_of(a.x, a.y, a.z);
        cid[1] = cell_of(a.w, b.x, b.y);
        cid[2] = cell_of(b.z, b.w, c.x);
        cid[3] = cell_of(c.y, c.z, c.w);
        #pragma unroll
        for (int i = 0; i < 4; ++i) {
            int* base = rec + ((size_t)cid[i] << 4);
            int slot = __hip_atomic_fetch_add(base, 1, __ATOMIC_RELAXED,
                                              __HIP_MEMORY_SCOPE_AGENT);
            if (slot < CAP) {
                base[1 + slot] = p0 + i;     // same 64-B line as the atomic
            } else {
                int s = atomicAdd(nspill, 1);
                if (s < SPILLCAP) { spill[2 * s] = cid[i]; spill[2 * s + 1] = p0 + i; }
            }
        }
    } else {
        for (int p = p0; p < n; ++p) {
            int c = cell_of(pts[3 * p], pts[3 * p + 1], pts[3 * p + 2]);
            int* base = rec + ((size_t)c << 4);
            int slot = __hip_atomic_fetch_add(base, 1, __ATOMIC_RELAXED,
                                              __HIP_MEMORY_SCOPE_AGENT);
            if (slot < CAP) {
                base[1 + slot] = p;
            } else {
                int s = atomicAdd(nspill, 1);
                if (s < SPILLCAP) { spill[2 * s] = c; spill[2 * s + 1] = p; }
            }
        }
    }
}

// One wave = 4 cells. grp = lane>>4 owns cell wave*4+grp; ch4 = lane&15 spans
// the 64-ch row as float4s. One 64-B record load (4x int4, issued together)
// delivers count + 15 slot indices; first 8 point rows fetched with clamped
// indices (empty/short cells clamp to slot0 or row 0 -> L1-hit dups), giving
// 8 independent gathers in flight. Slots 8..14 come from the already-loaded
// record registers (statically unrolled, rare). Output: contiguous 1 KB/wave.
__global__ __launch_bounds__(256) void reduce_bucket(
    const float4* __restrict__ feat4,
    const int* __restrict__ rec,
    const int* __restrict__ nspill,
    const int* __restrict__ spill,
    float4* __restrict__ out4)
{
    int lane = threadIdx.x & 63;
    int wave = (int)((blockIdx.x * blockDim.x + threadIdx.x) >> 6);
    int grp  = lane >> 4;
    int ch4  = lane & 15;
    int cell = wave * 4 + grp;          // grid sized exactly: cell < NCELLS

    const int4* r4 = (const int4*)(rec + ((size_t)cell << 4));
    int4 r0 = r4[0];                    // {cnt, s0, s1, s2}
    int4 r1 = r4[1];                    // {s3, s4, s5, s6}
    int4 r2 = r4[2];                    // {s7, s8, s9, s10}
    int4 r3 = r4[3];                    // {s11, s12, s13, s14}

    int cnt = r0.x;
    int len = min(cnt, CAP);
    int e0 = (len > 0) ? r0.y : 0;      // empty cell -> harmless row 0 read
    int e1 = (len > 1) ? r0.z : e0;
    int e2 = (len > 2) ? r0.w : e0;
    int e3 = (len > 3) ? r1.x : e0;
    int e4 = (len > 4) ? r1.y : e0;
    int e5 = (len > 5) ? r1.z : e0;
    int e6 = (len > 6) ? r1.w : e0;
    int e7 = (len > 7) ? r2.x : e0;

    const float4* fb = feat4 + ch4;
    float4 f0 = fb[(size_t)e0 * 16];
    float4 f1 = fb[(size_t)e1 * 16];
    float4 f2 = fb[(size_t)e2 * 16];
    float4 f3 = fb[(size_t)e3 * 16];
    float4 f4 = fb[(size_t)e4 * 16];
    float4 f5 = fb[(size_t)e5 * 16];
    float4 f6 = fb[(size_t)e6 * 16];
    float4 f7 = fb[(size_t)e7 * 16];

    float4 acc = make_float4(0.f, 0.f, 0.f, 0.f);
    if (len > 0) fadd4(acc, f0);
    if (len > 1) fadd4(acc, f1);
    if (len > 2) fadd4(acc, f2);
    if (len > 3) fadd4(acc, f3);
    if (len > 4) fadd4(acc, f4);
    if (len > 5) fadd4(acc, f5);
    if (len > 6) fadd4(acc, f6);
    if (len > 7) fadd4(acc, f7);

    if (len > 8) {                      // ~1.5% of cells; slots from registers
        fadd4(acc, fb[(size_t)r2.y * 16]);
        if (len > 9)  fadd4(acc, fb[(size_t)r2.z * 16]);
        if (len > 10) fadd4(acc, fb[(size_t)r2.w * 16]);
        if (len > 11) fadd4(acc, fb[(size_t)r3.x * 16]);
        if (len > 12) fadd4(acc, fb[(size_t)r3.y * 16]);
        if (len > 13) fadd4(acc, fb[(size_t)r3.z * 16]);
        if (len > 14) fadd4(acc, fb[(size_t)r3.w * 16]);
    }
    if (cnt > CAP) {                    // ~0.4 cells per grid; exactness guard
        int ns = min(*nspill, SPILLCAP);
        for (int s = 0; s < ns; ++s) {
            if (spill[2 * s] == cell) fadd4(acc, fb[(size_t)spill[2 * s + 1] * 16]);
        }
    }
    float inv = 1.0f / (float)max(cnt, 1);
    acc.x *= inv; acc.y *= inv; acc.z *= inv; acc.w *= inv;

    out4[(size_t)wave * 64 + lane] = acc;   // == out4[cell*16 + ch4], contiguous
}

extern "C" void kernel_launch(void* const* d_in, const int* in_sizes, int n_in,
                              void* d_out, int out_size, void* d_ws, size_t ws_size,
                              hipStream_t stream)
{
    const float* feat = (const float*)d_in[0];   // (N, 64) fp32
    const float* pts  = (const float*)d_in[1];   // (N, 3)  fp32
    float* out = (float*)d_out;                  // (64,64,64,64) fp32

    const int n = in_sizes[0] / NCH;

    // Workspace (ints): rec (NCELLS*16) | nspill (1, +3 pad) | spill (2*SPILLCAP)
    // Total: 4194304 + 4 + 16384 ints = ~16.8 MB
    int* rec    = (int*)d_ws;                    // NCELLS * 16, 64-B records
    int* nspill = rec + (size_t)NCELLS * 16;     // 1 (+3 pad)
    int* spill  = nspill + 4;                    // 2*SPILLCAP

    // Zero records + spill counter in one contiguous memset (16 MB, ~2.5 us).
    hipMemsetAsync(rec, 0, ((size_t)NCELLS * 16 + 4) * sizeof(int), stream);

    int t4 = (n + 3) / 4;
    int pblocks = (t4 + 255) / 256;
    assign_pts<<<pblocks, 256, 0, stream>>>(pts, rec, nspill, spill, n);

    // 65536 waves (4 cells each) = 16384 blocks of 4 waves.
    reduce_bucket<<<NCELLS / 16, 256, 0, stream>>>(
        (const float4*)feat, rec, nspill, spill, (float4*)out);
}